// Round 1
// baseline (541.659 us; speedup 1.0000x reference)
//
#include <hip/hip_runtime.h>
#include <stdint.h>

typedef __attribute__((ext_vector_type(4))) float f32x4;
typedef __attribute__((ext_vector_type(8))) __bf16 bf16x8;
typedef __attribute__((ext_vector_type(8))) unsigned short u16x8;

#define GLOBAL_AS __attribute__((address_space(1)))
#define LDS_AS    __attribute__((address_space(3)))

// async global->LDS, 16B per lane; LDS dest = wave-uniform base + lane*16
__device__ __forceinline__ void lds_load16(const void* g, void* l) {
  __builtin_amdgcn_global_load_lds((const GLOBAL_AS uint32_t*)(uintptr_t)g,
                                   (LDS_AS uint32_t*)(uintptr_t)l, 16, 0, 0);
}

__device__ __forceinline__ unsigned short f2bf(float f) {
  uint32_t u = __builtin_bit_cast(uint32_t, f);
  u += 0x7fffu + ((u >> 16) & 1u);   // RNE
  return (unsigned short)(u >> 16);
}

__global__ void cast_bf16(const float* __restrict__ in, unsigned short* __restrict__ out, int n) {
  int i = (blockIdx.x * 256 + threadIdx.x) * 4;
  if (i < n) {
    const float4 v = *(const float4*)(in + i);
    ushort4 o;
    o.x = f2bf(v.x); o.y = f2bf(v.y); o.z = f2bf(v.z); o.w = f2bf(v.w);
    *(ushort4*)(out + i) = o;
  }
}

// C[M,N] = A[M,K] * Bw[N,K]^T + bias
// STORE_MODE 0: fp32 row-major [M,N]
// STORE_MODE 1: bf16 scatter to [B,H,S,DK] with S=2048, H=16, DK=64 (m=b*2048+s, n=h*64+dk)
template<int STORE_MODE>
__global__ __launch_bounds__(256, 2)
void gemm_bt(const unsigned short* __restrict__ A,
             const unsigned short* __restrict__ Bw,
             const float* __restrict__ bias,
             void* __restrict__ Cout,
             int M, int N, int K)
{
  __shared__ __align__(16) unsigned short As[128 * 32];
  __shared__ __align__(16) unsigned short Bs[128 * 32];

  const int tid  = threadIdx.x;
  const int wave = tid >> 6;
  const int lane = tid & 63;
  const int wm = wave >> 1, wn = wave & 1;     // 2x2 wave grid, 64x64 each
  const int quad = lane >> 4, l15 = lane & 15;

  const int m0 = blockIdx.y * 128;
  const int n0 = blockIdx.x * 128;

  f32x4 acc[4][4];
#pragma unroll
  for (int i = 0; i < 4; ++i)
#pragma unroll
    for (int j = 0; j < 4; ++j) acc[i][j] = f32x4{0.f, 0.f, 0.f, 0.f};

  // staging: per wave 2 issues for A, 2 for B; each issue = 16 rows x 64B
  const int sr = lane >> 2;            // 0..15 row within issue
  const int sc = (lane & 3) * 8;       // bf16 col offset 0,8,16,24
  const unsigned short* Ag0 = A  + (size_t)(m0 + wave * 16 + sr) * K + sc;
  const unsigned short* Ag1 = Ag0 + (size_t)64 * K;
  const unsigned short* Bg0 = Bw + (size_t)(n0 + wave * 16 + sr) * K + sc;
  const unsigned short* Bg1 = Bg0 + (size_t)64 * K;
  unsigned short* AsW0 = &As[wave * 512];
  unsigned short* AsW1 = &As[2048 + wave * 512];
  unsigned short* BsW0 = &Bs[wave * 512];
  unsigned short* BsW1 = &Bs[2048 + wave * 512];

  for (int k0 = 0; k0 < K; k0 += 32) {
    lds_load16(Ag0 + k0, AsW0);
    lds_load16(Ag1 + k0, AsW1);
    lds_load16(Bg0 + k0, BsW0);
    lds_load16(Bg1 + k0, BsW1);
    __syncthreads();

    bf16x8 af[4], bfr[4];
#pragma unroll
    for (int i = 0; i < 4; ++i)
      af[i] = *(const bf16x8*)&As[(wm * 64 + i * 16 + l15) * 32 + quad * 8];
#pragma unroll
    for (int j = 0; j < 4; ++j)
      bfr[j] = *(const bf16x8*)&Bs[(wn * 64 + j * 16 + l15) * 32 + quad * 8];
#pragma unroll
    for (int i = 0; i < 4; ++i)
#pragma unroll
      for (int j = 0; j < 4; ++j)
        acc[i][j] = __builtin_amdgcn_mfma_f32_16x16x32_bf16(af[i], bfr[j], acc[i][j], 0, 0, 0);
    __syncthreads();
  }

  float bj[4];
#pragma unroll
  for (int j = 0; j < 4; ++j) bj[j] = bias[n0 + wn * 64 + j * 16 + l15];

#pragma unroll
  for (int i = 0; i < 4; ++i) {
    const int mbase = m0 + wm * 64 + i * 16 + quad * 4;   // C/D row = quad*4 + reg
#pragma unroll
    for (int j = 0; j < 4; ++j) {
      const int n = n0 + wn * 64 + j * 16 + l15;          // C/D col = lane&15
#pragma unroll
      for (int r = 0; r < 4; ++r) {
        const int m = mbase + r;
        const float vv = acc[i][j][r] + bj[j];
        if (STORE_MODE == 0) {
          ((float*)Cout)[(size_t)m * N + n] = vv;
        } else {
          const size_t idx = ((((size_t)(m >> 11) * 16 + (n >> 6)) << 11) + (size_t)(m & 2047)) * 64 + (n & 63);
          ((unsigned short*)Cout)[idx] = f2bf(vv);
        }
      }
    }
  }
}

// flash attention: 1 block = (b, h, 128 q rows); 4 waves x 32 q rows each.
// Q,K,V in [B,H,S,DK] bf16; output Xo in [B,S,H*DK] bf16.
__global__ __launch_bounds__(256, 2)
void flash_attn(const unsigned short* __restrict__ Qh,
                const unsigned short* __restrict__ Kh,
                const unsigned short* __restrict__ Vh,
                unsigned short* __restrict__ Xo)
{
  __shared__ __align__(16) unsigned short Qs[128 * 64];   // [q][d]
  __shared__ __align__(16) unsigned short Ks[128 * 64];   // [k][d]
  __shared__ __align__(16) unsigned short Vt[64 * 128];   // [d][k]  (V transposed)
  __shared__ __align__(16) unsigned short Ps[128 * 128];  // [q][k]

  const int qb = blockIdx.x, h = blockIdx.y, b = blockIdx.z;
  const int tid = threadIdx.x, wave = tid >> 6, lane = tid & 63;
  const int quad = lane >> 4, l15 = lane & 15;

  const size_t bh = (((size_t)b * 16 + h) << 17);          // * S*DK
  const unsigned short* Qg = Qh + bh + ((size_t)qb << 13); // * 128*64

  // stage Q tile (contiguous 16 KB)
#pragma unroll
  for (int p = 0; p < 4; ++p)
    lds_load16(Qg + (wave * 4 + p) * 512 + lane * 8, &Qs[(wave * 4 + p) * 512]);

  f32x4 oacc[2][4];
  float mrow[2][4], lrow[2][4];
#pragma unroll
  for (int i = 0; i < 2; ++i) {
#pragma unroll
    for (int jd = 0; jd < 4; ++jd) oacc[i][jd] = f32x4{0.f, 0.f, 0.f, 0.f};
#pragma unroll
    for (int r = 0; r < 4; ++r) { mrow[i][r] = -1e30f; lrow[i][r] = 0.f; }
  }

  const unsigned short* Kg = Kh + bh;
  const unsigned short* Vg = Vh + bh;
  const int vk = tid >> 1;             // 0..127: key row handled by this thread
  const int vdh = (tid & 1) * 32;      // which 32 d's

  for (int kb = 0; kb < 16; ++kb) {
    __syncthreads();   // previous iteration's LDS reads complete before restage
#pragma unroll
    for (int p = 0; p < 4; ++p)
      lds_load16(Kg + ((size_t)kb << 13) + (wave * 4 + p) * 512 + lane * 8,
                 &Ks[(wave * 4 + p) * 512]);
    {  // V transpose staging: Vt[d][k] = V[k][d]
      const unsigned short* vr = Vg + ((size_t)kb << 13) + vk * 64 + vdh;
#pragma unroll
      for (int c = 0; c < 4; ++c) {
        u16x8 vv = *(const u16x8*)(vr + c * 8);
#pragma unroll
        for (int e = 0; e < 8; ++e)
          Vt[(vdh + c * 8 + e) * 128 + vk] = vv[e];
      }
    }
    __syncthreads();

    // S = Q K^T  (wave's 32 q rows x 128 keys)
    f32x4 s[2][8];
#pragma unroll
    for (int i = 0; i < 2; ++i)
#pragma unroll
      for (int j = 0; j < 8; ++j) s[i][j] = f32x4{0.f, 0.f, 0.f, 0.f};
#pragma unroll
    for (int d = 0; d < 2; ++d) {
      bf16x8 aq[2];
#pragma unroll
      for (int i = 0; i < 2; ++i)
        aq[i] = *(const bf16x8*)&Qs[(wave * 32 + i * 16 + l15) * 64 + d * 32 + quad * 8];
#pragma unroll
      for (int j = 0; j < 8; ++j) {
        bf16x8 bk = *(const bf16x8*)&Ks[(j * 16 + l15) * 64 + d * 32 + quad * 8];
#pragma unroll
        for (int i = 0; i < 2; ++i)
          s[i][j] = __builtin_amdgcn_mfma_f32_16x16x32_bf16(aq[i], bk, s[i][j], 0, 0, 0);
      }
    }

    // online softmax; S rows in C/D layout: row=quad*4+reg, col=j*16+l15
#pragma unroll
    for (int i = 0; i < 2; ++i)
#pragma unroll
      for (int j = 0; j < 8; ++j) s[i][j] *= 0.125f;   // 1/sqrt(64)

    float alpha[2][4];
#pragma unroll
    for (int i = 0; i < 2; ++i) {
#pragma unroll
      for (int r = 0; r < 4; ++r) {
        float mx = s[i][0][r];
#pragma unroll
        for (int j = 1; j < 8; ++j) mx = fmaxf(mx, s[i][j][r]);
        mx = fmaxf(mx, __shfl_xor(mx, 1));
        mx = fmaxf(mx, __shfl_xor(mx, 2));
        mx = fmaxf(mx, __shfl_xor(mx, 4));
        mx = fmaxf(mx, __shfl_xor(mx, 8));
        const float mo = mrow[i][r];
        const float mn = fmaxf(mo, mx);
        mrow[i][r] = mn;
        const float al = __expf(mo - mn);
        alpha[i][r] = al;
        float rs = 0.f;
#pragma unroll
        for (int j = 0; j < 8; ++j) {
          const float p = __expf(s[i][j][r] - mn);
          s[i][j][r] = p;
          rs += p;
        }
        rs += __shfl_xor(rs, 1);
        rs += __shfl_xor(rs, 2);
        rs += __shfl_xor(rs, 4);
        rs += __shfl_xor(rs, 8);
        lrow[i][r] = lrow[i][r] * al + rs;
      }
    }

    // rescale O by alpha (rows match C/D reg layout)
#pragma unroll
    for (int i = 0; i < 2; ++i)
#pragma unroll
      for (int jd = 0; jd < 4; ++jd)
#pragma unroll
        for (int r = 0; r < 4; ++r) oacc[i][jd][r] *= alpha[i][r];

    // P -> LDS (C/D layout -> memory), own-wave rows only
#pragma unroll
    for (int i = 0; i < 2; ++i)
#pragma unroll
      for (int j = 0; j < 8; ++j)
#pragma unroll
        for (int r = 0; r < 4; ++r)
          Ps[(wave * 32 + i * 16 + quad * 4 + r) * 128 + j * 16 + l15] = f2bf(s[i][j][r]);

    asm volatile("" ::: "memory");  // compiler barrier: keep P writes before reads (DS is in-order per wave)

    // O += P V : A-frag from Ps (A[m=l15][k=quad*8+e]), B-frag from Vt
#pragma unroll
    for (int kk = 0; kk < 4; ++kk) {
      bf16x8 ap[2];
#pragma unroll
      for (int i = 0; i < 2; ++i)
        ap[i] = *(const bf16x8*)&Ps[(wave * 32 + i * 16 + l15) * 128 + kk * 32 + quad * 8];
#pragma unroll
      for (int jd = 0; jd < 4; ++jd) {
        bf16x8 bv = *(const bf16x8*)&Vt[(jd * 16 + l15) * 128 + kk * 32 + quad * 8];
#pragma unroll
        for (int i = 0; i < 2; ++i)
          oacc[i][jd] = __builtin_amdgcn_mfma_f32_16x16x32_bf16(ap[i], bv, oacc[i][jd], 0, 0, 0);
      }
    }
  }

  // epilogue: O / l, store bf16 to [B,S,H*DK]
#pragma unroll
  for (int i = 0; i < 2; ++i)
#pragma unroll
    for (int r = 0; r < 4; ++r) {
      const float inv = 1.f / lrow[i][r];
      const int srow = qb * 128 + wave * 32 + i * 16 + quad * 4 + r;
#pragma unroll
      for (int jd = 0; jd < 4; ++jd) {
        const int d = (h << 6) + jd * 16 + l15;
        Xo[(((size_t)b << 11) + srow) * 1024 + d] = f2bf(oacc[i][jd][r] * inv);
      }
    }
}

extern "C" void kernel_launch(void* const* d_in, const int* in_sizes, int n_in,
                              void* d_out, int out_size, void* d_ws, size_t ws_size,
                              hipStream_t stream) {
  const float* q  = (const float*)d_in[0];
  const float* k  = (const float*)d_in[1];
  const float* v  = (const float*)d_in[2];
  const float* Wq = (const float*)d_in[3];
  const float* bq = (const float*)d_in[4];
  const float* Wk = (const float*)d_in[5];
  const float* bk = (const float*)d_in[6];
  const float* Wv = (const float*)d_in[7];
  const float* bv = (const float*)d_in[8];
  const float* Wo = (const float*)d_in[9];
  const float* bo = (const float*)d_in[10];

  const int B = 4, S = 2048, D = 1024, H = 16;
  const size_t NX = (size_t)B * S * D;   // 8388608
  const size_t NW = (size_t)D * D;       // 1048576

  unsigned short* xq = (unsigned short*)d_ws;
  unsigned short* xk = xq + NX;
  unsigned short* xv = xk + NX;
  unsigned short* wq = xv + NX;
  unsigned short* wk = wq + NW;
  unsigned short* wv = wk + NW;
  unsigned short* wo = wv + NW;
  unsigned short* Qh = wo + NW;   // [B,H,S,DK]
  unsigned short* Kh = Qh + NX;
  unsigned short* Vh = Kh + NX;
  unsigned short* xo = Vh + NX;   // [B,S,D] attention output, bf16
  // total: 7*NX + 4*NW ushorts = ~125.8 MB of d_ws

  cast_bf16<<<(int)(NX / 1024), 256, 0, stream>>>(q,  xq, (int)NX);
  cast_bf16<<<(int)(NX / 1024), 256, 0, stream>>>(k,  xk, (int)NX);
  cast_bf16<<<(int)(NX / 1024), 256, 0, stream>>>(v,  xv, (int)NX);
  cast_bf16<<<(int)(NW / 1024), 256, 0, stream>>>(Wq, wq, (int)NW);
  cast_bf16<<<(int)(NW / 1024), 256, 0, stream>>>(Wk, wk, (int)NW);
  cast_bf16<<<(int)(NW / 1024), 256, 0, stream>>>(Wv, wv, (int)NW);
  cast_bf16<<<(int)(NW / 1024), 256, 0, stream>>>(Wo, wo, (int)NW);

  dim3 gg(D / 128, (B * S) / 128);  // (8, 64)
  gemm_bt<1><<<gg, 256, 0, stream>>>(xq, wq, bq, Qh, B * S, D, D);
  gemm_bt<1><<<gg, 256, 0, stream>>>(xk, wk, bk, Kh, B * S, D, D);
  gemm_bt<1><<<gg, 256, 0, stream>>>(xv, wv, bv, Vh, B * S, D, D);

  flash_attn<<<dim3(S / 128, H, B), 256, 0, stream>>>(Qh, Kh, Vh, xo);

  gemm_bt<0><<<gg, 256, 0, stream>>>(xo, wo, bo, d_out, B * S, D, D);
}

// Round 2
// 417.078 us; speedup vs baseline: 1.2987x; 1.2987x over previous
//
#include <hip/hip_runtime.h>
#include <stdint.h>

typedef __attribute__((ext_vector_type(4))) float f32x4;
typedef __attribute__((ext_vector_type(8))) __bf16 bf16x8;
typedef __attribute__((ext_vector_type(8))) unsigned short u16x8;

#define GLOBAL_AS __attribute__((address_space(1)))
#define LDS_AS    __attribute__((address_space(3)))

// async global->LDS, 16B per lane; LDS dest = wave-uniform base + lane*16
__device__ __forceinline__ void lds_load16(const void* g, void* l) {
  __builtin_amdgcn_global_load_lds((const GLOBAL_AS uint32_t*)(uintptr_t)g,
                                   (LDS_AS uint32_t*)(uintptr_t)l, 16, 0, 0);
}

__device__ __forceinline__ unsigned short f2bf(float f) {
  uint32_t u = __builtin_bit_cast(uint32_t, f);
  u += 0x7fffu + ((u >> 16) & 1u);   // RNE
  return (unsigned short)(u >> 16);
}

__device__ __forceinline__ uint32_t pk_bf16(float a, float b) {
#if __has_builtin(__builtin_amdgcn_cvt_pk_bf16_f32)
  return __builtin_bit_cast(uint32_t, __builtin_amdgcn_cvt_pk_bf16_f32(a, b));
#else
  return (uint32_t)f2bf(a) | ((uint32_t)f2bf(b) << 16);
#endif
}

__global__ void cast_bf16(const float* __restrict__ in, unsigned short* __restrict__ out, int n) {
  int i = (blockIdx.x * 256 + threadIdx.x) * 4;
  if (i < n) {
    const float4 v = *(const float4*)(in + i);
    ushort4 o;
    o.x = f2bf(v.x); o.y = f2bf(v.y); o.z = f2bf(v.z); o.w = f2bf(v.w);
    *(ushort4*)(out + i) = o;
  }
}

// C[M,N] = A[M,K] * Bw[N,K]^T + bias
// STORE_MODE 0: fp32 row-major [M,N], bias on n
// STORE_MODE 1: bf16 scatter to [B,H,S,DK] (S=2048,H=16,DK=64; m=b*2048+s, n=h*64+dk), bias on n
// STORE_MODE 2: bf16 row-major [M,N], bias on m  (used to produce V^T directly)
template<int STORE_MODE>
__global__ __launch_bounds__(256, 2)
void gemm_bt(const unsigned short* __restrict__ A,
             const unsigned short* __restrict__ Bw,
             const float* __restrict__ bias,
             void* __restrict__ Cout,
             int M, int N, int K)
{
  __shared__ __align__(16) unsigned short As[128 * 32];
  __shared__ __align__(16) unsigned short Bs[128 * 32];

  const int tid  = threadIdx.x;
  const int wave = tid >> 6;
  const int lane = tid & 63;
  const int wm = wave >> 1, wn = wave & 1;     // 2x2 wave grid, 64x64 each
  const int quad = lane >> 4, l15 = lane & 15;

  const int m0 = blockIdx.y * 128;
  const int n0 = blockIdx.x * 128;

  f32x4 acc[4][4];
#pragma unroll
  for (int i = 0; i < 4; ++i)
#pragma unroll
    for (int j = 0; j < 4; ++j) acc[i][j] = f32x4{0.f, 0.f, 0.f, 0.f};

  const int sr = lane >> 2;            // 0..15 row within issue
  const int sc = (lane & 3) * 8;       // bf16 col offset
  const unsigned short* Ag0 = A  + (size_t)(m0 + wave * 16 + sr) * K + sc;
  const unsigned short* Ag1 = Ag0 + (size_t)64 * K;
  const unsigned short* Bg0 = Bw + (size_t)(n0 + wave * 16 + sr) * K + sc;
  const unsigned short* Bg1 = Bg0 + (size_t)64 * K;
  unsigned short* AsW0 = &As[wave * 512];
  unsigned short* AsW1 = &As[2048 + wave * 512];
  unsigned short* BsW0 = &Bs[wave * 512];
  unsigned short* BsW1 = &Bs[2048 + wave * 512];

  for (int k0 = 0; k0 < K; k0 += 32) {
    lds_load16(Ag0 + k0, AsW0);
    lds_load16(Ag1 + k0, AsW1);
    lds_load16(Bg0 + k0, BsW0);
    lds_load16(Bg1 + k0, BsW1);
    __syncthreads();

    bf16x8 af[4], bfr[4];
#pragma unroll
    for (int i = 0; i < 4; ++i)
      af[i] = *(const bf16x8*)&As[(wm * 64 + i * 16 + l15) * 32 + quad * 8];
#pragma unroll
    for (int j = 0; j < 4; ++j)
      bfr[j] = *(const bf16x8*)&Bs[(wn * 64 + j * 16 + l15) * 32 + quad * 8];
#pragma unroll
    for (int i = 0; i < 4; ++i)
#pragma unroll
      for (int j = 0; j < 4; ++j)
        acc[i][j] = __builtin_amdgcn_mfma_f32_16x16x32_bf16(af[i], bfr[j], acc[i][j], 0, 0, 0);
    __syncthreads();
  }

  float bj[4];
  if (STORE_MODE != 2) {
#pragma unroll
    for (int j = 0; j < 4; ++j) bj[j] = bias[n0 + wn * 64 + j * 16 + l15];
  }

#pragma unroll
  for (int i = 0; i < 4; ++i) {
    const int mbase = m0 + wm * 64 + i * 16 + quad * 4;   // C/D row = quad*4 + reg
    float bm[4];
    if (STORE_MODE == 2) {
#pragma unroll
      for (int r = 0; r < 4; ++r) bm[r] = bias[mbase + r];
    }
#pragma unroll
    for (int j = 0; j < 4; ++j) {
      const int n = n0 + wn * 64 + j * 16 + l15;          // C/D col = lane&15
#pragma unroll
      for (int r = 0; r < 4; ++r) {
        const int m = mbase + r;
        const float vv = acc[i][j][r] + (STORE_MODE == 2 ? bm[r] : bj[j]);
        if (STORE_MODE == 0) {
          ((float*)Cout)[(size_t)m * N + n] = vv;
        } else if (STORE_MODE == 1) {
          const size_t idx = ((((size_t)(m >> 11) * 16 + (n >> 6)) << 11) + (size_t)(m & 2047)) * 64 + (n & 63);
          ((unsigned short*)Cout)[idx] = f2bf(vv);
        } else {
          ((unsigned short*)Cout)[(size_t)m * N + n] = f2bf(vv);
        }
      }
    }
  }
}

// flash attention v2: 1 block = (b, h, 128 q rows); 4 waves x 32 q rows each.
// Q,K in [B,H,S,DK] bf16; Vt in [D=1024][B*S=8192] bf16 (= V^T, rows e=h*64+dk);
// output Xo in [B,S,H*DK] bf16.
// LDS rows padded (+4 banks/row) -> conflict-free frag access.
// S^T = mfma(K,Q) so P-store is contiguous (ds_write_b64) and softmax needs
// only cross-quad shuffles. Q frags hoisted to registers (LDS region reused by Ps).
__global__ __launch_bounds__(256, 2)
void flash_attn(const unsigned short* __restrict__ Qh,
                const unsigned short* __restrict__ Kh,
                const unsigned short* __restrict__ VtG,
                unsigned short* __restrict__ Xo)
{
  __shared__ __align__(16) unsigned short Ks[128 * 72];   // [k][d], pad 8
  __shared__ __align__(16) unsigned short Vs[64 * 136];   // [d][k], pad 8
  __shared__ __align__(16) unsigned short Ps[128 * 136];  // [q][k], pad 8 (also initial Q staging)

  const int qb = blockIdx.x, h = blockIdx.y, b = blockIdx.z;
  const int tid = threadIdx.x, wave = tid >> 6, lane = tid & 63;
  const int quad = lane >> 4, l15 = lane & 15;

  const size_t bh = (((size_t)b * 16 + h) << 17);          // * S*DK
  const unsigned short* Qg = Qh + bh + ((size_t)qb << 13); // * 128*64
  const unsigned short* Kg = Kh + bh;
  const unsigned short* Vg = VtG + ((size_t)(h * 64)) * 8192 + (size_t)b * 2048;

  // ---- stage Q tile into Ps region (row stride 136), read frags, done with it
#pragma unroll
  for (int p = 0; p < 4; ++p) {
    const int c = tid + p * 256;                 // 16B chunk id, 0..1023
    u16x8 qv = *(const u16x8*)(Qg + c * 8);
    *(u16x8*)&Ps[(c >> 3) * 136 + (c & 7) * 8] = qv;
  }
  __syncthreads();
  bf16x8 aq[2][2];
#pragma unroll
  for (int i = 0; i < 2; ++i)
#pragma unroll
    for (int d = 0; d < 2; ++d)
      aq[i][d] = *(const bf16x8*)&Ps[(wave * 32 + i * 16 + l15) * 136 + d * 32 + quad * 8];

  f32x4 oacc[2][4];
  float mrow[2], lrow[2];
#pragma unroll
  for (int i = 0; i < 2; ++i) {
#pragma unroll
    for (int jd = 0; jd < 4; ++jd) oacc[i][jd] = f32x4{0.f, 0.f, 0.f, 0.f};
    mrow[i] = -1e30f; lrow[i] = 0.f;
  }

  // software-pipelined K/V tile loads
  u16x8 kreg[4], vreg[4];
#pragma unroll
  for (int p = 0; p < 4; ++p) {
    const int c = tid + p * 256;
    kreg[p] = *(const u16x8*)(Kg + c * 8);
    vreg[p] = *(const u16x8*)(Vg + (size_t)(c >> 4) * 8192 + (c & 15) * 8);
  }

  for (int kb = 0; kb < 16; ++kb) {
    __syncthreads();   // all waves done reading previous Ks/Vs
#pragma unroll
    for (int p = 0; p < 4; ++p) {
      const int c = tid + p * 256;
      *(u16x8*)&Ks[(c >> 3) * 72 + (c & 7) * 8] = kreg[p];
      *(u16x8*)&Vs[(c >> 4) * 136 + (c & 15) * 8] = vreg[p];
    }
    if (kb < 15) {
      const size_t ko = ((size_t)(kb + 1) << 13);
#pragma unroll
      for (int p = 0; p < 4; ++p) {
        const int c = tid + p * 256;
        kreg[p] = *(const u16x8*)(Kg + ko + c * 8);
        vreg[p] = *(const u16x8*)(Vg + (size_t)(c >> 4) * 8192 + (kb + 1) * 128 + (c & 15) * 8);
      }
    }
    __syncthreads();

    // S^T = K Q^T : C/D row (m) = k-within-tile, col (n) = q-within-16
    f32x4 s[2][8];
#pragma unroll
    for (int i = 0; i < 2; ++i)
#pragma unroll
      for (int j = 0; j < 8; ++j) s[i][j] = f32x4{0.f, 0.f, 0.f, 0.f};
#pragma unroll
    for (int d = 0; d < 2; ++d)
#pragma unroll
      for (int j = 0; j < 8; ++j) {
        bf16x8 kf = *(const bf16x8*)&Ks[(j * 16 + l15) * 72 + d * 32 + quad * 8];
#pragma unroll
        for (int i = 0; i < 2; ++i)
          s[i][j] = __builtin_amdgcn_mfma_f32_16x16x32_bf16(kf, aq[i][d], s[i][j], 0, 0, 0);
      }

    // online softmax over k; per lane: q = i*16+l15, 32 k-values (j x r) in this quad
#pragma unroll
    for (int i = 0; i < 2; ++i) {
      float mx = -1e30f;
#pragma unroll
      for (int j = 0; j < 8; ++j)
#pragma unroll
        for (int r = 0; r < 4; ++r) {
          s[i][j][r] *= 0.125f;                 // 1/sqrt(64)
          mx = fmaxf(mx, s[i][j][r]);
        }
      mx = fmaxf(mx, __shfl_xor(mx, 16));
      mx = fmaxf(mx, __shfl_xor(mx, 32));
      const float mo = mrow[i];
      const float mn = fmaxf(mo, mx);
      mrow[i] = mn;
      const float al = __expf(mo - mn);
      float rs = 0.f;
#pragma unroll
      for (int j = 0; j < 8; ++j)
#pragma unroll
        for (int r = 0; r < 4; ++r) {
          const float p = __expf(s[i][j][r] - mn);
          s[i][j][r] = p;
          rs += p;
        }
      rs += __shfl_xor(rs, 16);
      rs += __shfl_xor(rs, 32);
      lrow[i] = lrow[i] * al + rs;

      // rescale O rows: O C/D row = quad*4+r needs alpha of that q (held at lane q&15)
#pragma unroll
      for (int r = 0; r < 4; ++r) {
        const float aO = __shfl(al, quad * 4 + r);
#pragma unroll
        for (int jd = 0; jd < 4; ++jd) oacc[i][jd][r] *= aO;
      }

      // write P rows (own-wave, q-major, contiguous in r -> b64)
      const int prow = (wave * 32 + i * 16 + l15) * 136;
#pragma unroll
      for (int j = 0; j < 8; ++j) {
        uint2 pk;
        pk.x = pk_bf16(s[i][j][0], s[i][j][1]);
        pk.y = pk_bf16(s[i][j][2], s[i][j][3]);
        *(uint2*)&Ps[prow + j * 16 + quad * 4] = pk;
      }
    }

    asm volatile("" ::: "memory");  // keep P writes before P reads (same-wave DS is in-order)

    // O += P V : A-frag from Ps rows (own wave), B-frag from Vs [d][k]
#pragma unroll
    for (int kk = 0; kk < 4; ++kk) {
      bf16x8 ap[2];
#pragma unroll
      for (int i = 0; i < 2; ++i)
        ap[i] = *(const bf16x8*)&Ps[(wave * 32 + i * 16 + l15) * 136 + kk * 32 + quad * 8];
#pragma unroll
      for (int jd = 0; jd < 4; ++jd) {
        bf16x8 bv = *(const bf16x8*)&Vs[(jd * 16 + l15) * 136 + kk * 32 + quad * 8];
#pragma unroll
        for (int i = 0; i < 2; ++i)
          oacc[i][jd] = __builtin_amdgcn_mfma_f32_16x16x32_bf16(ap[i], bv, oacc[i][jd], 0, 0, 0);
      }
    }
  }

  // epilogue: O / l, store bf16 to [B,S,H*DK]; l held per-q at lane q&15 -> shuffle to rows
#pragma unroll
  for (int i = 0; i < 2; ++i)
#pragma unroll
    for (int r = 0; r < 4; ++r) {
      const float lO = __shfl(lrow[i], quad * 4 + r);
      const float inv = 1.f / lO;
      const int srow = qb * 128 + wave * 32 + i * 16 + quad * 4 + r;
      const size_t obase = (((size_t)b << 11) + srow) * 1024 + (h << 6);
#pragma unroll
      for (int jd = 0; jd < 4; ++jd)
        Xo[obase + jd * 16 + l15] = f2bf(oacc[i][jd][r] * inv);
    }
}

extern "C" void kernel_launch(void* const* d_in, const int* in_sizes, int n_in,
                              void* d_out, int out_size, void* d_ws, size_t ws_size,
                              hipStream_t stream) {
  const float* q  = (const float*)d_in[0];
  const float* k  = (const float*)d_in[1];
  const float* v  = (const float*)d_in[2];
  const float* Wq = (const float*)d_in[3];
  const float* bq = (const float*)d_in[4];
  const float* Wk = (const float*)d_in[5];
  const float* bk = (const float*)d_in[6];
  const float* Wv = (const float*)d_in[7];
  const float* bv = (const float*)d_in[8];
  const float* Wo = (const float*)d_in[9];
  const float* bo = (const float*)d_in[10];

  const int B = 4, S = 2048, D = 1024, H = 16;
  const size_t NX = (size_t)B * S * D;   // 8388608
  const size_t NW = (size_t)D * D;       // 1048576

  unsigned short* xq = (unsigned short*)d_ws;
  unsigned short* xk = xq + NX;
  unsigned short* xv = xk + NX;
  unsigned short* wq = xv + NX;
  unsigned short* wk = wq + NW;
  unsigned short* wv = wk + NW;
  unsigned short* wo = wv + NW;
  unsigned short* Qh = wo + NW;   // [B,H,S,DK]
  unsigned short* Kh = Qh + NX;
  unsigned short* Vt = Kh + NX;   // [D][B*S] = V^T
  unsigned short* xo = Vt + NX;   // [B,S,D] attention output, bf16

  cast_bf16<<<(int)(NX / 1024), 256, 0, stream>>>(q,  xq, (int)NX);
  cast_bf16<<<(int)(NX / 1024), 256, 0, stream>>>(k,  xk, (int)NX);
  cast_bf16<<<(int)(NX / 1024), 256, 0, stream>>>(v,  xv, (int)NX);
  cast_bf16<<<(int)(NW / 1024), 256, 0, stream>>>(Wq, wq, (int)NW);
  cast_bf16<<<(int)(NW / 1024), 256, 0, stream>>>(Wk, wk, (int)NW);
  cast_bf16<<<(int)(NW / 1024), 256, 0, stream>>>(Wv, wv, (int)NW);
  cast_bf16<<<(int)(NW / 1024), 256, 0, stream>>>(Wo, wo, (int)NW);

  dim3 gg(D / 128, (B * S) / 128);  // (8, 64)
  gemm_bt<1><<<gg, 256, 0, stream>>>(xq, wq, bq, Qh, B * S, D, D);
  gemm_bt<1><<<gg, 256, 0, stream>>>(xk, wk, bk, Kh, B * S, D, D);
  // V^T = Wv * Xv^T : A = Wv [1024][1024], Bw = Xv [8192][1024], bias on m
  gemm_bt<2><<<dim3((B * S) / 128, D / 128), 256, 0, stream>>>(wv, xv, bv, Vt, D, B * S, D);

  flash_attn<<<dim3(S / 128, H, B), 256, 0, stream>>>(Qh, Kh, Vt, xo);

  gemm_bt<0><<<gg, 256, 0, stream>>>(xo, wo, bo, d_out, B * S, D, D);
}

// Round 5
// 406.505 us; speedup vs baseline: 1.3325x; 1.0260x over previous
//
#include <hip/hip_runtime.h>
#include <stdint.h>

typedef __attribute__((ext_vector_type(4))) float f32x4;
typedef __attribute__((ext_vector_type(8))) __bf16 bf16x8;
typedef __attribute__((ext_vector_type(8))) unsigned short u16x8;

#define GLOBAL_AS __attribute__((address_space(1)))
#define LDS_AS    __attribute__((address_space(3)))

// async global->LDS, 16B per lane; LDS dest = wave-uniform base + lane*16
__device__ __forceinline__ void lds_load16(const void* g, void* l) {
  __builtin_amdgcn_global_load_lds((const GLOBAL_AS uint32_t*)(uintptr_t)g,
                                   (LDS_AS uint32_t*)(uintptr_t)l, 16, 0, 0);
}

__device__ __forceinline__ unsigned short f2bf(float f) {
  uint32_t u = __builtin_bit_cast(uint32_t, f);
  u += 0x7fffu + ((u >> 16) & 1u);   // RNE
  return (unsigned short)(u >> 16);
}

__device__ __forceinline__ uint32_t pk_bf16(float a, float b) {
#if __has_builtin(__builtin_amdgcn_cvt_pk_bf16_f32)
  return __builtin_bit_cast(uint32_t, __builtin_amdgcn_cvt_pk_bf16_f32(a, b));
#else
  return (uint32_t)f2bf(a) | ((uint32_t)f2bf(b) << 16);
#endif
}

// ---- fused cast: q,k,v (8192 blocks each) then Wq,Wk,Wv,Wo (1024 each).
// dst regions are contiguous in ws in exactly this order.
__global__ void cast_all(const float* __restrict__ q, const float* __restrict__ k,
                         const float* __restrict__ v, const float* __restrict__ Wq,
                         const float* __restrict__ Wk, const float* __restrict__ Wv,
                         const float* __restrict__ Wo, unsigned short* __restrict__ dst) {
  const int bid = blockIdx.x;
  const float* src;
  int rel;
  if (bid < 24576) {
    const int seg = bid >> 13;
    rel = bid & 8191;
    src = (seg == 0) ? q : (seg == 1) ? k : v;
  } else {
    const int w = (bid - 24576) >> 10;
    rel = (bid - 24576) & 1023;
    src = (w == 0) ? Wq : (w == 1) ? Wk : (w == 2) ? Wv : Wo;
  }
  const size_t di = (size_t)bid * 1024 + threadIdx.x * 4;
  const size_t si = (size_t)rel * 1024 + threadIdx.x * 4;
  const float4 val = *(const float4*)(src + si);
  ushort4 o;
  o.x = f2bf(val.x); o.y = f2bf(val.y); o.z = f2bf(val.z); o.w = f2bf(val.w);
  *(ushort4*)(dst + di) = o;
}

// ---- fused Q/K/V^T projection GEMMs — VALUE-IDENTICAL to R2's three
// verified gemm_bt launches (f2bf epilogues, NO ksc fold). Only the
// grid-map / pointer-select fusion differs. blockIdx.y selects:
//  y=0: Qh = xq*wq^T + bq   -> bf16 scatter [B,H,S,DK]
//  y=1: Kh = xk*wk^T + bk   -> bf16 scatter [B,H,S,DK]
//  y=2: Vt = wv*xv^T + bv(m)-> bf16 row-major [1024][8192] (= V^T)
__global__ __launch_bounds__(256, 2)
void gemm_qkv(const unsigned short* __restrict__ xq, const unsigned short* __restrict__ xk,
              const unsigned short* __restrict__ xv, const unsigned short* __restrict__ wq,
              const unsigned short* __restrict__ wk, const unsigned short* __restrict__ wv,
              const float* __restrict__ bq, const float* __restrict__ bk,
              const float* __restrict__ bv,
              unsigned short* __restrict__ Qh, unsigned short* __restrict__ Kh,
              unsigned short* __restrict__ Vt)
{
  __shared__ __align__(16) unsigned short As[128 * 32];
  __shared__ __align__(16) unsigned short Bs[128 * 32];

  const int gy = blockIdx.y, gx = blockIdx.x;
  const unsigned short* A  = (gy == 0) ? xq : (gy == 1) ? xk : wv;
  const unsigned short* Bw = (gy == 0) ? wq : (gy == 1) ? wk : xv;
  const float* bias        = (gy == 0) ? bq : (gy == 1) ? bk : bv;

  int m0, n0, N;
  if (gy < 2) { m0 = (gx >> 3) * 128; n0 = (gx & 7) * 128; N = 1024; }
  else        { m0 = (gx & 7) * 128;  n0 = (gx >> 3) * 128; N = 8192; }
  const int K = 1024;

  const int tid  = threadIdx.x;
  const int wave = tid >> 6;
  const int lane = tid & 63;
  const int wm = wave >> 1, wn = wave & 1;
  const int quad = lane >> 4, l15 = lane & 15;

  f32x4 acc[4][4];
#pragma unroll
  for (int i = 0; i < 4; ++i)
#pragma unroll
    for (int j = 0; j < 4; ++j) acc[i][j] = f32x4{0.f, 0.f, 0.f, 0.f};

  const int sr = lane >> 2;
  const int sc = (lane & 3) * 8;
  const unsigned short* Ag0 = A  + (size_t)(m0 + wave * 16 + sr) * K + sc;
  const unsigned short* Ag1 = Ag0 + (size_t)64 * K;
  const unsigned short* Bg0 = Bw + (size_t)(n0 + wave * 16 + sr) * K + sc;
  const unsigned short* Bg1 = Bg0 + (size_t)64 * K;
  unsigned short* AsW0 = &As[wave * 512];
  unsigned short* AsW1 = &As[2048 + wave * 512];
  unsigned short* BsW0 = &Bs[wave * 512];
  unsigned short* BsW1 = &Bs[2048 + wave * 512];

  for (int k0 = 0; k0 < K; k0 += 32) {
    lds_load16(Ag0 + k0, AsW0);
    lds_load16(Ag1 + k0, AsW1);
    lds_load16(Bg0 + k0, BsW0);
    lds_load16(Bg1 + k0, BsW1);
    __syncthreads();

    bf16x8 af[4], bfr[4];
#pragma unroll
    for (int i = 0; i < 4; ++i)
      af[i] = *(const bf16x8*)&As[(wm * 64 + i * 16 + l15) * 32 + quad * 8];
#pragma unroll
    for (int j = 0; j < 4; ++j)
      bfr[j] = *(const bf16x8*)&Bs[(wn * 64 + j * 16 + l15) * 32 + quad * 8];
#pragma unroll
    for (int i = 0; i < 4; ++i)
#pragma unroll
      for (int j = 0; j < 4; ++j)
        acc[i][j] = __builtin_amdgcn_mfma_f32_16x16x32_bf16(af[i], bfr[j], acc[i][j], 0, 0, 0);
    __syncthreads();
  }

  if (gy < 2) {
    // scatter store to [B,H,S,DK] — R2's exact epilogue (f2bf, no scale)
    unsigned short* out = (gy == 0) ? Qh : Kh;
    float bj[4];
#pragma unroll
    for (int j = 0; j < 4; ++j) bj[j] = bias[n0 + wn * 64 + j * 16 + l15];
#pragma unroll
    for (int i = 0; i < 4; ++i) {
      const int mbase = m0 + wm * 64 + i * 16 + quad * 4;
#pragma unroll
      for (int j = 0; j < 4; ++j) {
        const int n = n0 + wn * 64 + j * 16 + l15;
#pragma unroll
        for (int r = 0; r < 4; ++r) {
          const int m = mbase + r;
          const float vv = acc[i][j][r] + bj[j];
          const size_t idx = ((((size_t)(m >> 11) * 16 + (n >> 6)) << 11) + (size_t)(m & 2047)) * 64 + (n & 63);
          out[idx] = f2bf(vv);
        }
      }
    }
  } else {
    // V^T: bf16 row-major [1024][8192], bias on m — R2's exact epilogue
#pragma unroll
    for (int i = 0; i < 4; ++i) {
      const int mbase = m0 + wm * 64 + i * 16 + quad * 4;
      float bm[4];
#pragma unroll
      for (int r = 0; r < 4; ++r) bm[r] = bias[mbase + r];
#pragma unroll
      for (int j = 0; j < 4; ++j) {
        const int n = n0 + wn * 64 + j * 16 + l15;
#pragma unroll
        for (int r = 0; r < 4; ++r)
          Vt[(size_t)(mbase + r) * N + n] = f2bf(acc[i][j][r] + bm[r]);
      }
    }
  }
}

// ---- flash attention: R2's VERIFIED kernel, VERBATIM. 1 block = (b,h,128 q);
// 4 waves x 32 q. Q,K in [B,H,S,DK] bf16; Vt in [1024][8192] bf16 (V^T);
// output Xo bf16 [B,S,H*DK].
__global__ __launch_bounds__(256, 2)
void flash_attn(const unsigned short* __restrict__ Qh,
                const unsigned short* __restrict__ Kh,
                const unsigned short* __restrict__ VtG,
                unsigned short* __restrict__ Xo)
{
  __shared__ __align__(16) unsigned short Ks[128 * 72];   // [k][d], pad 8
  __shared__ __align__(16) unsigned short Vs[64 * 136];   // [d][k], pad 8
  __shared__ __align__(16) unsigned short Ps[128 * 136];  // [q][k], pad 8 (also initial Q staging)

  const int qb = blockIdx.x, h = blockIdx.y, b = blockIdx.z;
  const int tid = threadIdx.x, wave = tid >> 6, lane = tid & 63;
  const int quad = lane >> 4, l15 = lane & 15;

  const size_t bh = (((size_t)b * 16 + h) << 17);          // * S*DK
  const unsigned short* Qg = Qh + bh + ((size_t)qb << 13); // * 128*64
  const unsigned short* Kg = Kh + bh;
  const unsigned short* Vg = VtG + ((size_t)(h * 64)) * 8192 + (size_t)b * 2048;

  // ---- stage Q tile into Ps region (row stride 136), read frags, done with it
#pragma unroll
  for (int p = 0; p < 4; ++p) {
    const int c = tid + p * 256;                 // 16B chunk id, 0..1023
    u16x8 qv = *(const u16x8*)(Qg + c * 8);
    *(u16x8*)&Ps[(c >> 3) * 136 + (c & 7) * 8] = qv;
  }
  __syncthreads();
  bf16x8 aq[2][2];
#pragma unroll
  for (int i = 0; i < 2; ++i)
#pragma unroll
    for (int d = 0; d < 2; ++d)
      aq[i][d] = *(const bf16x8*)&Ps[(wave * 32 + i * 16 + l15) * 136 + d * 32 + quad * 8];

  f32x4 oacc[2][4];
  float mrow[2], lrow[2];
#pragma unroll
  for (int i = 0; i < 2; ++i) {
#pragma unroll
    for (int jd = 0; jd < 4; ++jd) oacc[i][jd] = f32x4{0.f, 0.f, 0.f, 0.f};
    mrow[i] = -1e30f; lrow[i] = 0.f;
  }

  // software-pipelined K/V tile loads
  u16x8 kreg[4], vreg[4];
#pragma unroll
  for (int p = 0; p < 4; ++p) {
    const int c = tid + p * 256;
    kreg[p] = *(const u16x8*)(Kg + c * 8);
    vreg[p] = *(const u16x8*)(Vg + (size_t)(c >> 4) * 8192 + (c & 15) * 8);
  }

  for (int kb = 0; kb < 16; ++kb) {
    __syncthreads();   // all waves done reading previous Ks/Vs
#pragma unroll
    for (int p = 0; p < 4; ++p) {
      const int c = tid + p * 256;
      *(u16x8*)&Ks[(c >> 3) * 72 + (c & 7) * 8] = kreg[p];
      *(u16x8*)&Vs[(c >> 4) * 136 + (c & 15) * 8] = vreg[p];
    }
    if (kb < 15) {
      const size_t ko = ((size_t)(kb + 1) << 13);
#pragma unroll
      for (int p = 0; p < 4; ++p) {
        const int c = tid + p * 256;
        kreg[p] = *(const u16x8*)(Kg + ko + c * 8);
        vreg[p] = *(const u16x8*)(Vg + (size_t)(c >> 4) * 8192 + (kb + 1) * 128 + (c & 15) * 8);
      }
    }
    __syncthreads();

    // S^T = K Q^T : C/D row (m) = k-within-tile, col (n) = q-within-16
    f32x4 s[2][8];
#pragma unroll
    for (int i = 0; i < 2; ++i)
#pragma unroll
      for (int j = 0; j < 8; ++j) s[i][j] = f32x4{0.f, 0.f, 0.f, 0.f};
#pragma unroll
    for (int d = 0; d < 2; ++d)
#pragma unroll
      for (int j = 0; j < 8; ++j) {
        bf16x8 kf = *(const bf16x8*)&Ks[(j * 16 + l15) * 72 + d * 32 + quad * 8];
#pragma unroll
        for (int i = 0; i < 2; ++i)
          s[i][j] = __builtin_amdgcn_mfma_f32_16x16x32_bf16(kf, aq[i][d], s[i][j], 0, 0, 0);
      }

    // online softmax over k; per lane: q = i*16+l15, 32 k-values (j x r) in this quad
#pragma unroll
    for (int i = 0; i < 2; ++i) {
      float mx = -1e30f;
#pragma unroll
      for (int j = 0; j < 8; ++j)
#pragma unroll
        for (int r = 0; r < 4; ++r) {
          s[i][j][r] *= 0.125f;                 // 1/sqrt(64)
          mx = fmaxf(mx, s[i][j][r]);
        }
      mx = fmaxf(mx, __shfl_xor(mx, 16));
      mx = fmaxf(mx, __shfl_xor(mx, 32));
      const float mo = mrow[i];
      const float mn = fmaxf(mo, mx);
      mrow[i] = mn;
      const float al = __expf(mo - mn);
      float rs = 0.f;
#pragma unroll
      for (int j = 0; j < 8; ++j)
#pragma unroll
        for (int r = 0; r < 4; ++r) {
          const float p = __expf(s[i][j][r] - mn);
          s[i][j][r] = p;
          rs += p;
        }
      rs += __shfl_xor(rs, 16);
      rs += __shfl_xor(rs, 32);
      lrow[i] = lrow[i] * al + rs;

      // rescale O rows: O C/D row = quad*4+r needs alpha of that q (held at lane q&15)
#pragma unroll
      for (int r = 0; r < 4; ++r) {
        const float aO = __shfl(al, quad * 4 + r);
#pragma unroll
        for (int jd = 0; jd < 4; ++jd) oacc[i][jd][r] *= aO;
      }

      // write P rows (own-wave, q-major, contiguous in r -> b64)
      const int prow = (wave * 32 + i * 16 + l15) * 136;
#pragma unroll
      for (int j = 0; j < 8; ++j) {
        uint2 pk;
        pk.x = pk_bf16(s[i][j][0], s[i][j][1]);
        pk.y = pk_bf16(s[i][j][2], s[i][j][3]);
        *(uint2*)&Ps[prow + j * 16 + quad * 4] = pk;
      }
    }

    asm volatile("" ::: "memory");  // keep P writes before P reads (same-wave DS is in-order)

    // O += P V : A-frag from Ps rows (own wave), B-frag from Vs [d][k]
#pragma unroll
    for (int kk = 0; kk < 4; ++kk) {
      bf16x8 ap[2];
#pragma unroll
      for (int i = 0; i < 2; ++i)
        ap[i] = *(const bf16x8*)&Ps[(wave * 32 + i * 16 + l15) * 136 + kk * 32 + quad * 8];
#pragma unroll
      for (int jd = 0; jd < 4; ++jd) {
        bf16x8 bv = *(const bf16x8*)&Vs[(jd * 16 + l15) * 136 + kk * 32 + quad * 8];
#pragma unroll
        for (int i = 0; i < 2; ++i)
          oacc[i][jd] = __builtin_amdgcn_mfma_f32_16x16x32_bf16(ap[i], bv, oacc[i][jd], 0, 0, 0);
      }
    }
  }

  // epilogue: O / l, store bf16 to [B,S,H*DK]; l held per-q at lane q&15 -> shuffle to rows
#pragma unroll
  for (int i = 0; i < 2; ++i)
#pragma unroll
    for (int r = 0; r < 4; ++r) {
      const float lO = __shfl(lrow[i], quad * 4 + r);
      const float inv = 1.f / lO;
      const int srow = qb * 128 + wave * 32 + i * 16 + quad * 4 + r;
      const size_t obase = (((size_t)b << 11) + srow) * 1024 + (h << 6);
#pragma unroll
      for (int jd = 0; jd < 4; ++jd)
        Xo[obase + jd * 16 + l15] = f2bf(oacc[i][jd][r] * inv);
    }
}

// ---- output projection: fp32 row-major, bias on n (R2's verified gemm_bt<0>)
__global__ __launch_bounds__(256, 2)
void gemm_out(const unsigned short* __restrict__ A,
              const unsigned short* __restrict__ Bw,
              const float* __restrict__ bias,
              float* __restrict__ Cout)
{
  __shared__ __align__(16) unsigned short As[128 * 32];
  __shared__ __align__(16) unsigned short Bs[128 * 32];

  const int tid  = threadIdx.x;
  const int wave = tid >> 6;
  const int lane = tid & 63;
  const int wm = wave >> 1, wn = wave & 1;
  const int quad = lane >> 4, l15 = lane & 15;
  const int m0 = blockIdx.y * 128;
  const int n0 = blockIdx.x * 128;
  const int K = 1024, N = 1024;

  f32x4 acc[4][4];
#pragma unroll
  for (int i = 0; i < 4; ++i)
#pragma unroll
    for (int j = 0; j < 4; ++j) acc[i][j] = f32x4{0.f, 0.f, 0.f, 0.f};

  const int sr = lane >> 2;
  const int sc = (lane & 3) * 8;
  const unsigned short* Ag0 = A  + (size_t)(m0 + wave * 16 + sr) * K + sc;
  const unsigned short* Ag1 = Ag0 + (size_t)64 * K;
  const unsigned short* Bg0 = Bw + (size_t)(n0 + wave * 16 + sr) * K + sc;
  const unsigned short* Bg1 = Bg0 + (size_t)64 * K;
  unsigned short* AsW0 = &As[wave * 512];
  unsigned short* AsW1 = &As[2048 + wave * 512];
  unsigned short* BsW0 = &Bs[wave * 512];
  unsigned short* BsW1 = &Bs[2048 + wave * 512];

  for (int k0 = 0; k0 < K; k0 += 32) {
    lds_load16(Ag0 + k0, AsW0);
    lds_load16(Ag1 + k0, AsW1);
    lds_load16(Bg0 + k0, BsW0);
    lds_load16(Bg1 + k0, BsW1);
    __syncthreads();

    bf16x8 af[4], bfr[4];
#pragma unroll
    for (int i = 0; i < 4; ++i)
      af[i] = *(const bf16x8*)&As[(wm * 64 + i * 16 + l15) * 32 + quad * 8];
#pragma unroll
    for (int j = 0; j < 4; ++j)
      bfr[j] = *(const bf16x8*)&Bs[(wn * 64 + j * 16 + l15) * 32 + quad * 8];
#pragma unroll
    for (int i = 0; i < 4; ++i)
#pragma unroll
      for (int j = 0; j < 4; ++j)
        acc[i][j] = __builtin_amdgcn_mfma_f32_16x16x32_bf16(af[i], bfr[j], acc[i][j], 0, 0, 0);
    __syncthreads();
  }

  float bj[4];
#pragma unroll
  for (int j = 0; j < 4; ++j) bj[j] = bias[n0 + wn * 64 + j * 16 + l15];

#pragma unroll
  for (int i = 0; i < 4; ++i) {
    const int mbase = m0 + wm * 64 + i * 16 + quad * 4;
#pragma unroll
    for (int j = 0; j < 4; ++j) {
      const int n = n0 + wn * 64 + j * 16 + l15;
#pragma unroll
      for (int r = 0; r < 4; ++r)
        Cout[(size_t)(mbase + r) * N + n] = acc[i][j][r] + bj[j];
    }
  }
}

extern "C" void kernel_launch(void* const* d_in, const int* in_sizes, int n_in,
                              void* d_out, int out_size, void* d_ws, size_t ws_size,
                              hipStream_t stream) {
  const float* q  = (const float*)d_in[0];
  const float* k  = (const float*)d_in[1];
  const float* v  = (const float*)d_in[2];
  const float* Wq = (const float*)d_in[3];
  const float* bq = (const float*)d_in[4];
  const float* Wk = (const float*)d_in[5];
  const float* bk = (const float*)d_in[6];
  const float* Wv = (const float*)d_in[7];
  const float* bv = (const float*)d_in[8];
  const float* Wo = (const float*)d_in[9];
  const float* bo = (const float*)d_in[10];

  const int B = 4, S = 2048, D = 1024, H = 16;
  const size_t NX = (size_t)B * S * D;   // 8388608
  const size_t NW = (size_t)D * D;       // 1048576

  unsigned short* xq = (unsigned short*)d_ws;
  unsigned short* xk = xq + NX;
  unsigned short* xv = xk + NX;
  unsigned short* wq = xv + NX;
  unsigned short* wk = wq + NW;
  unsigned short* wv = wk + NW;
  unsigned short* wo = wv + NW;
  unsigned short* Qh = wo + NW;   // [B,H,S,DK]
  unsigned short* Kh = Qh + NX;   // [B,H,S,DK]
  unsigned short* Vt = Kh + NX;   // [D][B*S] = V^T
  unsigned short* xo = Vt + NX;   // [B,S,D] attention output, bf16

  // 1 dispatch: all 7 casts (dst regions contiguous: xq,xk,xv,wq,wk,wv,wo)
  cast_all<<<28672, 256, 0, stream>>>(q, k, v, Wq, Wk, Wv, Wo, xq);

  // 1 dispatch: Q, K, V^T projections (value-identical to R2's three launches)
  gemm_qkv<<<dim3(512, 3), 256, 0, stream>>>(xq, xk, xv, wq, wk, wv, bq, bk, bv, Qh, Kh, Vt);

  // R2's verified flash, verbatim (128-q tiles)
  flash_attn<<<dim3(S / 128, H, B), 256, 0, stream>>>(Qh, Kh, Vt, xo);

  gemm_out<<<dim3(D / 128, (B * S) / 128), 256, 0, stream>>>(xo, wo, bo, (float*)d_out);
}